// Round 6
// baseline (368.045 us; speedup 1.0000x reference)
//
#include <hip/hip_runtime.h>
#include <hip/hip_bf16.h>
#include <stdint.h>

// Problem constants
#define DD (1 << 20)   // D = D1*D2 = 1048576
// N=8, D1=1024, D2=1024, B=1024
#define NPART 4096     // stats partial blocks

typedef float v4f __attribute__((ext_vector_type(4)));
typedef __bf16 bf16x8 __attribute__((ext_vector_type(8)));

struct Scalars {
  float s;             // step size at this stage
  int   uniform;       // 1 if all rows in one group (saturated sigmoid case)
  float coef[8];       // gradg[gid[i]] per sorted position i
  float cnti[8];       // max(counts[gid[i]],1) per sorted position i
  int   isend[8];      // 1 if sorted position i ends its group
};

struct Partial {       // per-block gap stats (no atomics for values -> deterministic)
  double g[7];
  double mx;
};

static __device__ __forceinline__ unsigned short f2bf(float v) {
  unsigned u = __float_as_uint(v);
  u += 0x7fffu + ((u >> 16) & 1u);   // round-to-nearest-even
  return (unsigned short)(u >> 16);
}

// ---------------- min/max -> s0 ----------------
__global__ void k_minmax_partial(const float4* __restrict__ U4, float2* __restrict__ part) {
  int tid = threadIdx.x, bid = blockIdx.x;
  float mn = 3.4e38f, mx = -3.4e38f;
#pragma unroll
  for (int j = 0; j < 8; ++j) {
    float4 v = U4[(size_t)(bid * 8 + j) * 256 + tid];
    mn = fminf(mn, fminf(fminf(v.x, v.y), fminf(v.z, v.w)));
    mx = fmaxf(mx, fmaxf(fmaxf(v.x, v.y), fmaxf(v.z, v.w)));
  }
#pragma unroll
  for (int off = 32; off; off >>= 1) {
    mn = fminf(mn, __shfl_down(mn, off, 64));
    mx = fmaxf(mx, __shfl_down(mx, off, 64));
  }
  __shared__ float2 w4[4];
  if ((tid & 63) == 0) w4[tid >> 6] = make_float2(mn, mx);
  __syncthreads();
  if (tid == 0) {
    for (int i = 1; i < 4; ++i) { mn = fminf(mn, w4[i].x); mx = fmaxf(mx, w4[i].y); }
    part[bid] = make_float2(mn, mx);
  }
}

// finishes minmax AND zero-inits the last-block counters for the stats kernels
__global__ void k_minmax_final(const float2* __restrict__ part, Scalars* sc0,
                               unsigned* __restrict__ cnt) {
  int tid = threadIdx.x;
  float mn = 3.4e38f, mx = -3.4e38f;
#pragma unroll
  for (int j = 0; j < 4; ++j) {
    float2 p = part[j * 256 + tid];
    mn = fminf(mn, p.x); mx = fmaxf(mx, p.y);
  }
#pragma unroll
  for (int off = 32; off; off >>= 1) {
    mn = fminf(mn, __shfl_down(mn, off, 64));
    mx = fmaxf(mx, __shfl_down(mx, off, 64));
  }
  __shared__ float2 w4[4];
  if ((tid & 63) == 0) w4[tid >> 6] = make_float2(mn, mx);
  __syncthreads();
  if (tid == 0) {
    for (int i = 1; i < 4; ++i) { mn = fminf(mn, w4[i].x); mx = fmaxf(mx, w4[i].y); }
    sc0->s = (mx - mn) / 3.0f;   // RES_DENOS[0] = 3.0, fp32 exact mirror
    cnt[0] = 0u;                 // counters for stats0 / stats1 last-block detection
    cnt[1] = 0u;
  }
}

// keyed 19-CE Batcher network; lexicographic (val, idx) == stable argsort
#define CE2(a, b)                                                        \
  { float ra = r[a], rb = r[b]; int oa = ord[a], ob = ord[b];            \
    bool sw = (ra > rb) || (ra == rb && oa > ob);                        \
    r[a] = sw ? rb : ra; r[b] = sw ? ra : rb;                            \
    ord[a] = sw ? ob : oa; ord[b] = sw ? oa : ob; }

#define SORTNET8                                                          \
  CE2(0,1) CE2(2,3) CE2(4,5) CE2(6,7)                                     \
  CE2(0,2) CE2(1,3) CE2(4,6) CE2(5,7)                                     \
  CE2(1,2) CE2(5,6)                                                       \
  CE2(0,4) CE2(1,5) CE2(2,6) CE2(3,7)                                     \
  CE2(2,4) CE2(3,5)                                                       \
  CE2(1,2) CE2(3,4) CE2(5,6)

// value-only network (stats / uniform path need only sorted values)
#define CEV(a, b) { float ra = q[a], rb = q[b]; q[a] = fminf(ra, rb); q[b] = fmaxf(ra, rb); }
#define SORTNET8V                                                         \
  CEV(0,1) CEV(2,3) CEV(4,5) CEV(6,7)                                     \
  CEV(0,2) CEV(1,3) CEV(4,6) CEV(5,7)                                     \
  CEV(1,2) CEV(5,6)                                                       \
  CEV(0,4) CEV(1,5) CEV(2,6) CEV(3,7)                                     \
  CEV(2,4) CEV(3,5)                                                       \
  CEV(1,2) CEV(3,4) CEV(5,6)

// block-reduce 7 gap sums + max, write to part[bid] (thread 0 does the store)
static __device__ __forceinline__ void stats_block_reduce(float dl[7], float mx,
                                                          Partial* __restrict__ po) {
#pragma unroll
  for (int off = 32; off; off >>= 1) {
#pragma unroll
    for (int g = 0; g < 7; ++g) dl[g] += __shfl_down(dl[g], off, 64);
    mx = fmaxf(mx, __shfl_down(mx, off, 64));
  }
  __shared__ double wsum[4][7];
  __shared__ float wmax[4];
  int lane = threadIdx.x & 63, wv = threadIdx.x >> 6;
  if (lane == 0) {
#pragma unroll
    for (int g = 0; g < 7; ++g) wsum[wv][g] = (double)dl[g];
    wmax[wv] = mx;
  }
  __syncthreads();
  if (threadIdx.x == 0) {
#pragma unroll
    for (int g = 0; g < 7; ++g)
      po->g[g] = wsum[0][g] + wsum[1][g] + wsum[2][g] + wsum[3][g];
    po->mx = (double)fmaxf(fmaxf(wmax[0], wmax[1]), fmaxf(wmax[2], wmax[3]));
  }
}

// 256-thread final reduce over NPART partials + 7-scalar group logic (run by ONE block)
static __device__ __forceinline__ void scalars_body(const Partial* __restrict__ part,
                                                    const Scalars* __restrict__ scin,
                                                    Scalars* __restrict__ scout,
                                                    const float* __restrict__ thres,
                                                    float deno) {
  int t = threadIdx.x;
  double g[7] = {0, 0, 0, 0, 0, 0, 0};
  double mx = 0.0;
#pragma unroll
  for (int j = 0; j < NPART / 256; ++j) {
    const Partial& p = part[j * 256 + t];
#pragma unroll
    for (int i = 0; i < 7; ++i) g[i] += p.g[i];
    mx = fmax(mx, p.mx);
  }
#pragma unroll
  for (int off = 32; off; off >>= 1) {
#pragma unroll
    for (int i = 0; i < 7; ++i) g[i] += __shfl_down(g[i], off, 64);
    mx = fmax(mx, __shfl_down(mx, off, 64));
  }
  __shared__ double sg[4][8];
  int lane = t & 63, wv = t >> 6;
  if (lane == 0) {
#pragma unroll
    for (int i = 0; i < 7; ++i) sg[wv][i] = g[i];
    sg[wv][7] = mx;
  }
  __syncthreads();
  if (t != 0) return;
#pragma unroll
  for (int i = 0; i < 7; ++i) g[i] = sg[0][i] + sg[1][i] + sg[2][i] + sg[3][i];
  mx = fmax(fmax(sg[0][7], sg[1][7]), fmax(sg[2][7], sg[3][7]));

  float s = scin->s / deno;
  scout->s = s;
  float md = (float)mx;
  float sigT = 1.f / (1.f + expf(-thres[0]));
  float sp[7], bb[7];
  for (int gg = 0; gg < 7; ++gg) {
    float mean = (float)(g[gg] / ((double)DD * (double)md));
    float z = (mean - sigT) / 0.01f;     // SPLIT_TEMP
    sp[gg] = 1.f / (1.f + expf(-z));
    bb[gg] = rintf(sp[gg]);              // jnp.round = RNE
  }
  int gid[8]; gid[0] = 0;
  for (int i = 1; i < 8; ++i) gid[i] = gid[i - 1] + (int)bb[i - 1];
  float counts[8] = {0, 0, 0, 0, 0, 0, 0, 0};
  for (int i = 0; i < 8; ++i) counts[gid[i]] += 1.f;
  float lsum[8] = {0, 0, 0, 0, 0, 0, 0, 0};
  for (int i = 0; i < 7; ++i) {
    float f = (bb[i] == 1.f) ? sp[i] : (1.f - sp[i]);
    lsum[gid[i]] += logf(f);
  }
  float gradg[8];
  for (int gg = 0; gg < 8; ++gg) gradg[gg] = expf(lsum[gg]);
  for (int i = 0; i < 8; ++i) {
    scout->coef[i] = gradg[gid[i]];
    scout->cnti[i] = fmaxf(counts[gid[i]], 1.f);
    scout->isend[i] = (i == 7) || (gid[i + 1] != gid[i]);
  }
  scout->uniform = (gid[7] == 0) ? 1 : 0;   // single group -> delta identical for all rows
}

// after this block's partial is visible, the LAST block to arrive runs scalars_body
static __device__ __forceinline__ void lastblock_scalars(Partial* __restrict__ part,
                                                         unsigned* __restrict__ cnt,
                                                         const Scalars* __restrict__ scin,
                                                         Scalars* __restrict__ scout,
                                                         const float* __restrict__ thres,
                                                         float deno) {
  __shared__ int islast;
  if (threadIdx.x == 0) {
    __threadfence();                       // release this block's partial
    unsigned old = atomicAdd(cnt, 1u);     // device-scope
    islast = (old == NPART - 1) ? 1 : 0;
  }
  __syncthreads();
  if (islast) {
    __threadfence();                       // acquire all partials
    scalars_body(part, scin, scout, thres, deno);
  }
}

// ---------------- general per-column update core (keyed sort + scatter) ----------------
static __device__ __forceinline__ void update_core(const float u[8], const float vo[8],
                                                   const Scalars* __restrict__ sc,
                                                   float vnew[8]) {
  float s = sc->s;
  float coef[8], cnti[8]; int isend[8];
#pragma unroll
  for (int i = 0; i < 8; ++i) { coef[i] = sc->coef[i]; cnti[i] = sc->cnti[i]; isend[i] = sc->isend[i]; }
  float r[8]; int ord[8];
#pragma unroll
  for (int n = 0; n < 8; ++n) { r[n] = u[n] - vo[n]; ord[n] = n; }
  SORTNET8
  float endsum[8]; float a = 0.f;
#pragma unroll
  for (int i = 0; i < 8; ++i) { a += r[i]; endsum[i] = a; if (isend[i]) a = 0.f; }
  float t[8]; float gsv = 0.f;
#pragma unroll
  for (int i = 7; i >= 0; --i) {
    if (isend[i]) gsv = endsum[i];
    t[i] = coef[i] * (gsv / cnti[i]);
  }
#pragma unroll
  for (int n = 0; n < 8; ++n) {
    float tv = 0.f;
#pragma unroll
    for (int i = 0; i < 8; ++i) tv = (ord[i] == n) ? t[i] : tv;
    vnew[n] = vo[n] + s * floorf(tv / s);
  }
}

// uniform (single-group) core: value-sort for the bit-exact sorted-order sum; same c for all
static __device__ __forceinline__ float uniform_delta(const float u[8], const float vo[8],
                                                      float coef0, float cnt0, float s) {
  float q[8];
#pragma unroll
  for (int n = 0; n < 8; ++n) q[n] = u[n] - vo[n];
  SORTNET8V
  float a = 0.f;
#pragma unroll
  for (int i = 0; i < 8; ++i) a += q[i];
  float t = coef0 * (a / cnt0);
  return s * floorf(t / s);
}

static __device__ __forceinline__ void apply_update(const float u[8], const float vo[8],
                                                    const Scalars* __restrict__ sc,
                                                    float vnew[8]) {
  if (sc->uniform) {
    float c = uniform_delta(u, vo, sc->coef[0], sc->cnti[0], sc->s);
#pragma unroll
    for (int n = 0; n < 8; ++n) vnew[n] = vo[n] + c;
  } else {
    update_core(u, vo, sc, vnew);
  }
}

// ---------------- stage-1 stats (v0 recomputed in regs) + x pack + last-block scalars --
// blocks [0,NPART): gap stats after level0; blocks [NPART, NPART+2048): pack x -> xT
__global__ void k_stats0(const float* __restrict__ U, Partial* __restrict__ part,
                         const Scalars* __restrict__ sc0, Scalars* __restrict__ sc1,
                         const float* __restrict__ thres, unsigned* __restrict__ cnt,
                         const float* __restrict__ x, unsigned short* __restrict__ xT) {
  int t = threadIdx.x;
  if (blockIdx.x < NPART) {
    int d = blockIdx.x * 256 + t;
    float s = sc0->s;
    float q[8];
#pragma unroll
    for (int n = 0; n < 8; ++n) {
      float u = U[((size_t)n << 20) + d];
      q[n] = u - s * floorf(u / s);
    }
    SORTNET8V
    float dl[7]; float mx = 0.f;
#pragma unroll
    for (int g = 0; g < 7; ++g) { dl[g] = q[g + 1] - q[g]; mx = fmaxf(mx, dl[g]); }
    stats_block_reduce(dl, mx, &part[blockIdx.x]);
    lastblock_scalars(part, cnt, sc0, sc1, thres, 5.0f);   // RES_DENOS[1]
  } else {
    int bid2 = blockIdx.x - NPART;          // 0..2047
#pragma unroll
    for (int j = 0; j < 4; ++j) {
      int i = j * (2048 * 256) + bid2 * 256 + t;
      int kq = i & 255;
      int b  = (i >> 8) & 1023;
      int n  = i >> 18;
      float4 v = *(const float4*)(x + ((size_t)(b * 8 + n) << 10) + (kq << 2));
      ushort4 o = make_ushort4(f2bf(v.x), f2bf(v.y), f2bf(v.z), f2bf(v.w));
      *(ushort4*)(xT + (((size_t)(n << 10 | b)) << 10) + (kq << 2)) = o;
    }
  }
}

// ---------------- stage-2 stats: recompute v0, apply update-1, stats, last-block scalars
__global__ void k_stats1(const float* __restrict__ U, Partial* __restrict__ part,
                         const Scalars* __restrict__ sc0, const Scalars* __restrict__ sc1,
                         Scalars* __restrict__ sc2, const float* __restrict__ thres,
                         unsigned* __restrict__ cnt) {
  int d = blockIdx.x * 256 + threadIdx.x;
  float s0 = sc0->s;
  float u[8], v0[8], v1[8];
#pragma unroll
  for (int n = 0; n < 8; ++n) {
    u[n] = U[((size_t)n << 20) + d];
    v0[n] = s0 * floorf(u[n] / s0);
  }
  apply_update(u, v0, sc1, v1);
  float q[8];
#pragma unroll
  for (int n = 0; n < 8; ++n) q[n] = u[n] - v1[n];
  SORTNET8V
  float dl[7]; float mx = 0.f;
#pragma unroll
  for (int g = 0; g < 7; ++g) { dl[g] = q[g + 1] - q[g]; mx = fmaxf(mx, dl[g]); }
  stats_block_reduce(dl, mx, &part[blockIdx.x]);
  lastblock_scalars(part, cnt + 1, sc1, sc2, thres, 17.0f);  // RES_DENOS[2]
}

// ---------------- final: recompute v0 -> v1 -> v2, bf16, LDS transpose -> wT[n][l][k] --
__global__ void k_final_pack(const float* __restrict__ U,
                             const Scalars* __restrict__ sc0, const Scalars* __restrict__ sc1,
                             const Scalars* __restrict__ sc2, unsigned short* __restrict__ wT) {
  __shared__ unsigned short stile[8][32][34];
  int t = threadIdx.x;
  int k0 = (blockIdx.x >> 5) * 32;
  int l0 = (blockIdx.x & 31) * 32;
  float s0 = sc0->s;
  int kk = t >> 3;            // 0..31
  int lq = t & 7;             // 4 cols each
  int d0 = (k0 + kk) * 1024 + l0 + lq * 4;
  float4 u4[8];
#pragma unroll
  for (int n = 0; n < 8; ++n) u4[n] = *(const float4*)(U + ((size_t)n << 20) + d0);
#pragma unroll
  for (int j = 0; j < 4; ++j) {
    float u[8], v0[8], v1[8], v2[8];
#pragma unroll
    for (int n = 0; n < 8; ++n) {
      u[n] = ((const float*)&u4[n])[j];
      v0[n] = s0 * floorf(u[n] / s0);
    }
    apply_update(u, v0, sc1, v1);
    apply_update(u, v1, sc2, v2);
#pragma unroll
    for (int n = 0; n < 8; ++n) stile[n][kk][lq * 4 + j] = f2bf(v2[n]);
  }
  __syncthreads();
  // write wT[n][l][k]: thread -> ll = t>>3, kq = t&7 (4 k's, ushort4)
  int ll = t >> 3, kq = t & 7;
#pragma unroll
  for (int n = 0; n < 8; ++n) {
    ushort4 o;
    o.x = stile[n][kq * 4 + 0][ll];
    o.y = stile[n][kq * 4 + 1][ll];
    o.z = stile[n][kq * 4 + 2][ll];
    o.w = stile[n][kq * 4 + 3][ll];
    *(ushort4*)(wT + ((size_t)n << 20) + (size_t)(l0 + ll) * 1024 + k0 + kq * 4) = o;
  }
}

// ---------------- batched GEMM: out[b][n][l] = sum_k xT[n][b][k] * wT[n][l][k] ----------------
// n = blockIdx.x so XCD (= linear bid % 8) pins one ensemble member per XCD:
// xT_n (2MB) + wT_n (2MB) fit the 4MB per-XCD L2 -> HBM fetch ~32MB instead of ~144MB.
// 128x128 C-tile per block, BK=64, 4 waves (2x2 of 64x64), 16x16x32 bf16 MFMA.
// LDS stored as 16B chunks with XOR swizzle: chunk (row, cc) holds global (row, cc ^ (row&7)).
__global__ __launch_bounds__(256, 2)
void k_gemm(const unsigned short* __restrict__ xT, const unsigned short* __restrict__ wT,
            float* __restrict__ out) {
  __shared__ bf16x8 sA[1024];   // 128 rows x 8 chunks = 16 KB
  __shared__ bf16x8 sB[1024];
  const int n  = blockIdx.x;
  const int m0 = blockIdx.y * 128;
  const int l0 = blockIdx.z * 128;
  const int tid = threadIdx.x;
  const int lane = tid & 63;
  const int wv = tid >> 6;
  const int wm = (wv & 1) * 64;
  const int wl = (wv >> 1) * 64;
  const unsigned short* A  = xT + ((size_t)n << 20);
  const unsigned short* Bt = wT + ((size_t)n << 20);

  v4f acc[4][4] = {};
  const int quad = lane >> 4;
  const int r16 = lane & 15;

  for (int kt = 0; kt < 1024; kt += 64) {
#pragma unroll
    for (int rr = 0; rr < 4; ++rr) {
      int cb = rr * 4 + wv;            // chunk-block 0..15
      int c = cb * 64 + lane;          // chunk 0..1023
      int row = c >> 3;
      int gc = (c & 7) ^ (row & 7);    // swizzled source column
      const unsigned short* ga = A  + (size_t)(m0 + row) * 1024 + kt + gc * 8;
      const unsigned short* gb = Bt + (size_t)(l0 + row) * 1024 + kt + gc * 8;
      __builtin_amdgcn_global_load_lds((const __attribute__((address_space(1))) void*)ga,
                                       (__attribute__((address_space(3))) void*)&sA[cb * 64],
                                       16, 0, 0);
      __builtin_amdgcn_global_load_lds((const __attribute__((address_space(1))) void*)gb,
                                       (__attribute__((address_space(3))) void*)&sB[cb * 64],
                                       16, 0, 0);
    }
    asm volatile("s_waitcnt vmcnt(0)" ::: "memory");
    __syncthreads();

#pragma unroll
    for (int ks = 0; ks < 2; ++ks) {
      bf16x8 af[4], bfr[4];
#pragma unroll
      for (int t = 0; t < 4; ++t) {
        int arow = wm + t * 16 + r16;
        af[t] = sA[arow * 8 + ((ks * 4 + quad) ^ (arow & 7))];
        int brow = wl + t * 16 + r16;
        bfr[t] = sB[brow * 8 + ((ks * 4 + quad) ^ (brow & 7))];
      }
#pragma unroll
      for (int tm = 0; tm < 4; ++tm)
#pragma unroll
        for (int tn = 0; tn < 4; ++tn)
          acc[tm][tn] = __builtin_amdgcn_mfma_f32_16x16x32_bf16(af[tm], bfr[tn], acc[tm][tn], 0, 0, 0);
    }
    __syncthreads();
  }

  // epilogue: D[m=quad*4+reg][l=lane&15] per 16x16 tile
#pragma unroll
  for (int tm = 0; tm < 4; ++tm)
#pragma unroll
    for (int tn = 0; tn < 4; ++tn)
#pragma unroll
      for (int rr = 0; rr < 4; ++rr) {
        int row = m0 + wm + tm * 16 + quad * 4 + rr;
        int col = l0 + wl + tn * 16 + r16;
        out[(size_t)(row * 8 + n) * 1024 + col] = acc[tm][tn][rr];
      }
}

extern "C" void kernel_launch(void* const* d_in, const int* in_sizes, int n_in,
                              void* d_out, int out_size, void* d_ws, size_t ws_size,
                              hipStream_t stream) {
  const float* x = (const float*)d_in[0];
  const float* U = (const float*)d_in[1];
  const float* thres = (const float*)d_in[2];
  float* out = (float*)d_out;

  char* w = (char*)d_ws;
  Scalars* sc = (Scalars*)w;                                  // sc[0..2]
  unsigned* cnt = (unsigned*)(w + 2048);                      // 2 last-block counters
  float2* mmpart = (float2*)(w + 4096);                       // 8 KB
  unsigned short* xT = (unsigned short*)(w + 16384);          // 16 MB
  unsigned short* wT = xT + ((size_t)8 << 20);                // 16 MB
  Partial* part = (Partial*)(w + 16384 + ((size_t)32 << 20)); // 256 KB

  k_minmax_partial<<<1024, 256, 0, stream>>>((const float4*)U, mmpart);
  k_minmax_final<<<1, 256, 0, stream>>>(mmpart, &sc[0], cnt);
  k_stats0<<<NPART + 2048, 256, 0, stream>>>(U, part, &sc[0], &sc[1], thres, cnt, x, xT);
  k_stats1<<<NPART, 256, 0, stream>>>(U, part, &sc[0], &sc[1], &sc[2], thres, cnt);
  k_final_pack<<<1024, 256, 0, stream>>>(U, &sc[0], &sc[1], &sc[2], wT);
  k_gemm<<<dim3(8, 8, 8), 256, 0, stream>>>(xT, wT, out);
}

// Round 7
// 165.684 us; speedup vs baseline: 2.2214x; 2.2214x over previous
//
#include <hip/hip_runtime.h>
#include <hip/hip_bf16.h>
#include <stdint.h>

// Problem constants
#define DD (1 << 20)   // D = D1*D2 = 1048576
// N=8, D1=1024, D2=1024, B=1024
#define NPART 4096     // stats partial blocks

typedef float v4f __attribute__((ext_vector_type(4)));
typedef __bf16 bf16x8 __attribute__((ext_vector_type(8)));

struct Scalars {
  float s;             // step size at this stage
  int   uniform;       // 1 if all rows in one group (saturated sigmoid case)
  int   done;          // 1 if this stage was derived analytically (skip its stats pass)
  float coef[8];       // gradg[gid[i]] per sorted position i
  float cnti[8];       // max(counts[gid[i]],1) per sorted position i
  int   isend[8];      // 1 if sorted position i ends its group
};

struct Partial {       // per-block gap stats (no atomics -> deterministic, no fences)
  double g[7];
  double mx;
};

static __device__ __forceinline__ unsigned short f2bf(float v) {
  unsigned u = __float_as_uint(v);
  u += 0x7fffu + ((u >> 16) & 1u);   // round-to-nearest-even
  return (unsigned short)(u >> 16);
}

// ---------------- min/max -> s0 ----------------
__global__ void k_minmax_partial(const float4* __restrict__ U4, float2* __restrict__ part) {
  int tid = threadIdx.x, bid = blockIdx.x;
  float mn = 3.4e38f, mx = -3.4e38f;
#pragma unroll
  for (int j = 0; j < 8; ++j) {
    float4 v = U4[(size_t)(bid * 8 + j) * 256 + tid];
    mn = fminf(mn, fminf(fminf(v.x, v.y), fminf(v.z, v.w)));
    mx = fmaxf(mx, fmaxf(fmaxf(v.x, v.y), fmaxf(v.z, v.w)));
  }
#pragma unroll
  for (int off = 32; off; off >>= 1) {
    mn = fminf(mn, __shfl_down(mn, off, 64));
    mx = fmaxf(mx, __shfl_down(mx, off, 64));
  }
  __shared__ float2 w4[4];
  if ((tid & 63) == 0) w4[tid >> 6] = make_float2(mn, mx);
  __syncthreads();
  if (tid == 0) {
    for (int i = 1; i < 4; ++i) { mn = fminf(mn, w4[i].x); mx = fmaxf(mx, w4[i].y); }
    part[bid] = make_float2(mn, mx);
  }
}

__global__ void k_minmax_final(const float2* __restrict__ part, Scalars* sc0) {
  int tid = threadIdx.x;
  float mn = 3.4e38f, mx = -3.4e38f;
#pragma unroll
  for (int j = 0; j < 4; ++j) {
    float2 p = part[j * 256 + tid];
    mn = fminf(mn, p.x); mx = fmaxf(mx, p.y);
  }
#pragma unroll
  for (int off = 32; off; off >>= 1) {
    mn = fminf(mn, __shfl_down(mn, off, 64));
    mx = fmaxf(mx, __shfl_down(mx, off, 64));
  }
  __shared__ float2 w4[4];
  if ((tid & 63) == 0) w4[tid >> 6] = make_float2(mn, mx);
  __syncthreads();
  if (tid == 0) {
    for (int i = 1; i < 4; ++i) { mn = fminf(mn, w4[i].x); mx = fmaxf(mx, w4[i].y); }
    sc0->s = (mx - mn) / 3.0f;   // RES_DENOS[0] = 3.0, fp32 exact mirror
  }
}

// keyed 19-CE Batcher network; lexicographic (val, idx) == stable argsort
#define CE2(a, b)                                                        \
  { float ra = r[a], rb = r[b]; int oa = ord[a], ob = ord[b];            \
    bool sw = (ra > rb) || (ra == rb && oa > ob);                        \
    r[a] = sw ? rb : ra; r[b] = sw ? ra : rb;                            \
    ord[a] = sw ? ob : oa; ord[b] = sw ? oa : ob; }

#define SORTNET8                                                          \
  CE2(0,1) CE2(2,3) CE2(4,5) CE2(6,7)                                     \
  CE2(0,2) CE2(1,3) CE2(4,6) CE2(5,7)                                     \
  CE2(1,2) CE2(5,6)                                                       \
  CE2(0,4) CE2(1,5) CE2(2,6) CE2(3,7)                                     \
  CE2(2,4) CE2(3,5)                                                       \
  CE2(1,2) CE2(3,4) CE2(5,6)

// value-only network (stats / uniform path need only sorted values)
#define CEV(a, b) { float ra = q[a], rb = q[b]; q[a] = fminf(ra, rb); q[b] = fmaxf(ra, rb); }
#define SORTNET8V                                                         \
  CEV(0,1) CEV(2,3) CEV(4,5) CEV(6,7)                                     \
  CEV(0,2) CEV(1,3) CEV(4,6) CEV(5,7)                                     \
  CEV(1,2) CEV(5,6)                                                       \
  CEV(0,4) CEV(1,5) CEV(2,6) CEV(3,7)                                     \
  CEV(2,4) CEV(3,5)                                                       \
  CEV(1,2) CEV(3,4) CEV(5,6)

// block-reduce 7 gap sums + max, write to part[blockIdx.x]
static __device__ __forceinline__ void stats_block_reduce(float dl[7], float mx,
                                                          Partial* __restrict__ po) {
#pragma unroll
  for (int off = 32; off; off >>= 1) {
#pragma unroll
    for (int g = 0; g < 7; ++g) dl[g] += __shfl_down(dl[g], off, 64);
    mx = fmaxf(mx, __shfl_down(mx, off, 64));
  }
  __shared__ double wsum[4][7];
  __shared__ float wmax[4];
  int lane = threadIdx.x & 63, wv = threadIdx.x >> 6;
  if (lane == 0) {
#pragma unroll
    for (int g = 0; g < 7; ++g) wsum[wv][g] = (double)dl[g];
    wmax[wv] = mx;
  }
  __syncthreads();
  if (threadIdx.x == 0) {
#pragma unroll
    for (int g = 0; g < 7; ++g)
      po->g[g] = wsum[0][g] + wsum[1][g] + wsum[2][g] + wsum[3][g];
    po->mx = (double)fmaxf(fmaxf(wmax[0], wmax[1]), fmaxf(wmax[2], wmax[3]));
  }
}

// ---------------- reduce partials + 7-scalar group logic ----------------
// If check_done and scout->done: stage already derived analytically -> skip.
// If scnext != null and this stage is uniform with huge sigmoid margin, derive the
// NEXT stage analytically: r_next = r - c (per-column constant) => gaps identical up to
// ~1e-7 fp noise => b=0 everywhere; sp < e^-21 => sum(sp) < 2^-26 => 1-sp == 1.0f in
// fp32 => gradg == 1.0f bit-exactly; counts == 8. So scnext = {s/deno_next, uniform,
// coef=1, cnti=8} is bit-identical to running the full stats pass.
__global__ void k_scalars2(const Partial* __restrict__ part, const Scalars* __restrict__ scin,
                           Scalars* __restrict__ scout, Scalars* __restrict__ scnext,
                           const float* __restrict__ thres, float deno, float deno_next,
                           int check_done) {
  if (check_done && scout->done) return;
  int t = threadIdx.x;   // 256 threads; NPART partials
  double g[7] = {0, 0, 0, 0, 0, 0, 0};
  double mx = 0.0;
#pragma unroll
  for (int j = 0; j < NPART / 256; ++j) {
    const Partial& p = part[j * 256 + t];
#pragma unroll
    for (int i = 0; i < 7; ++i) g[i] += p.g[i];
    mx = fmax(mx, p.mx);
  }
#pragma unroll
  for (int off = 32; off; off >>= 1) {
#pragma unroll
    for (int i = 0; i < 7; ++i) g[i] += __shfl_down(g[i], off, 64);
    mx = fmax(mx, __shfl_down(mx, off, 64));
  }
  __shared__ double sg[4][8];
  int lane = t & 63, wv = t >> 6;
  if (lane == 0) {
#pragma unroll
    for (int i = 0; i < 7; ++i) sg[wv][i] = g[i];
    sg[wv][7] = mx;
  }
  __syncthreads();
  if (t != 0) return;
#pragma unroll
  for (int i = 0; i < 7; ++i) g[i] = sg[0][i] + sg[1][i] + sg[2][i] + sg[3][i];
  mx = fmax(fmax(sg[0][7], sg[1][7]), fmax(sg[2][7], sg[3][7]));

  float s = scin->s / deno;
  scout->s = s;
  float md = (float)mx;
  float sigT = 1.f / (1.f + expf(-thres[0]));
  float sp[7], bb[7];
  float zmax = -1e30f;
  for (int gg = 0; gg < 7; ++gg) {
    float mean = (float)(g[gg] / ((double)DD * (double)md));
    float z = (mean - sigT) / 0.01f;     // SPLIT_TEMP
    zmax = fmaxf(zmax, z);
    sp[gg] = 1.f / (1.f + expf(-z));
    bb[gg] = rintf(sp[gg]);              // jnp.round = RNE
  }
  int gid[8]; gid[0] = 0;
  for (int i = 1; i < 8; ++i) gid[i] = gid[i - 1] + (int)bb[i - 1];
  float counts[8] = {0, 0, 0, 0, 0, 0, 0, 0};
  for (int i = 0; i < 8; ++i) counts[gid[i]] += 1.f;
  float lsum[8] = {0, 0, 0, 0, 0, 0, 0, 0};
  for (int i = 0; i < 7; ++i) {
    float f = (bb[i] == 1.f) ? sp[i] : (1.f - sp[i]);
    lsum[gid[i]] += logf(f);
  }
  float gradg[8];
  for (int gg = 0; gg < 8; ++gg) gradg[gg] = expf(lsum[gg]);
  for (int i = 0; i < 8; ++i) {
    scout->coef[i] = gradg[gid[i]];
    scout->cnti[i] = fmaxf(counts[gid[i]], 1.f);
    scout->isend[i] = (i == 7) || (gid[i + 1] != gid[i]);
  }
  int uni = (gid[7] == 0) ? 1 : 0;
  scout->uniform = uni;

  if (scnext) {
    if (uni && zmax < -21.0f) {          // saturation certain -> next stage analytic
      scnext->s = s / deno_next;
      scnext->uniform = 1;
#pragma unroll
      for (int i = 0; i < 8; ++i) {
        scnext->coef[i] = 1.0f;
        scnext->cnti[i] = 8.0f;
        scnext->isend[i] = (i == 7) ? 1 : 0;
      }
      scnext->done = 1;
    } else {
      scnext->done = 0;                  // fallback: full stats pass will fill it
    }
  }
}

// ---------------- general per-column update core (keyed sort + scatter) ----------------
static __device__ __forceinline__ void update_core(const float u[8], const float vo[8],
                                                   const Scalars* __restrict__ sc,
                                                   float vnew[8]) {
  float s = sc->s;
  float coef[8], cnti[8]; int isend[8];
#pragma unroll
  for (int i = 0; i < 8; ++i) { coef[i] = sc->coef[i]; cnti[i] = sc->cnti[i]; isend[i] = sc->isend[i]; }
  float r[8]; int ord[8];
#pragma unroll
  for (int n = 0; n < 8; ++n) { r[n] = u[n] - vo[n]; ord[n] = n; }
  SORTNET8
  float endsum[8]; float a = 0.f;
#pragma unroll
  for (int i = 0; i < 8; ++i) { a += r[i]; endsum[i] = a; if (isend[i]) a = 0.f; }
  float t[8]; float gsv = 0.f;
#pragma unroll
  for (int i = 7; i >= 0; --i) {
    if (isend[i]) gsv = endsum[i];
    t[i] = coef[i] * (gsv / cnti[i]);
  }
#pragma unroll
  for (int n = 0; n < 8; ++n) {
    float tv = 0.f;
#pragma unroll
    for (int i = 0; i < 8; ++i) tv = (ord[i] == n) ? t[i] : tv;
    vnew[n] = vo[n] + s * floorf(tv / s);
  }
}

// uniform (single-group) core: value-sort for the bit-exact sorted-order sum; same c for all
static __device__ __forceinline__ float uniform_delta(const float u[8], const float vo[8],
                                                      float coef0, float cnt0, float s) {
  float q[8];
#pragma unroll
  for (int n = 0; n < 8; ++n) q[n] = u[n] - vo[n];
  SORTNET8V
  float a = 0.f;
#pragma unroll
  for (int i = 0; i < 8; ++i) a += q[i];
  float t = coef0 * (a / cnt0);
  return s * floorf(t / s);
}

static __device__ __forceinline__ void apply_update(const float u[8], const float vo[8],
                                                    const Scalars* __restrict__ sc,
                                                    float vnew[8]) {
  if (sc->uniform) {
    float c = uniform_delta(u, vo, sc->coef[0], sc->cnti[0], sc->s);
#pragma unroll
    for (int n = 0; n < 8; ++n) vnew[n] = vo[n] + c;
  } else {
    update_core(u, vo, sc, vnew);
  }
}

// ---------------- stage-1 stats (v0 recomputed in regs, never stored) + x pack ---------
// blocks [0,NPART): gap stats after level0; blocks [NPART, NPART+2048): pack x -> xT
__global__ void k_stats0(const float* __restrict__ U, Partial* __restrict__ part,
                         const Scalars* __restrict__ sc0,
                         const float* __restrict__ x, unsigned short* __restrict__ xT) {
  int t = threadIdx.x;
  if (blockIdx.x < NPART) {
    int d = blockIdx.x * 256 + t;
    float s = sc0->s;
    float q[8];
#pragma unroll
    for (int n = 0; n < 8; ++n) {
      float u = U[((size_t)n << 20) + d];
      q[n] = u - s * floorf(u / s);
    }
    SORTNET8V
    float dl[7]; float mx = 0.f;
#pragma unroll
    for (int g = 0; g < 7; ++g) { dl[g] = q[g + 1] - q[g]; mx = fmaxf(mx, dl[g]); }
    stats_block_reduce(dl, mx, &part[blockIdx.x]);
  } else {
    int bid2 = blockIdx.x - NPART;          // 0..2047
#pragma unroll
    for (int j = 0; j < 4; ++j) {
      int i = j * (2048 * 256) + bid2 * 256 + t;
      int kq = i & 255;
      int b  = (i >> 8) & 1023;
      int n  = i >> 18;
      float4 v = *(const float4*)(x + ((size_t)(b * 8 + n) << 10) + (kq << 2));
      ushort4 o = make_ushort4(f2bf(v.x), f2bf(v.y), f2bf(v.z), f2bf(v.w));
      *(ushort4*)(xT + (((size_t)(n << 10 | b)) << 10) + (kq << 2)) = o;
    }
  }
}

// ---------------- stage-2 stats: recompute v0, apply update-1 in regs, stats -----------
// Early-exits if stage 2 was derived analytically (sc2->done).
__global__ void k_stats1(const float* __restrict__ U, Partial* __restrict__ part,
                         const Scalars* __restrict__ sc0, const Scalars* __restrict__ sc1,
                         const Scalars* __restrict__ sc2) {
  if (sc2->done) return;
  int d = blockIdx.x * 256 + threadIdx.x;
  float s0 = sc0->s;
  float u[8], v0[8], v1[8];
#pragma unroll
  for (int n = 0; n < 8; ++n) {
    u[n] = U[((size_t)n << 20) + d];
    v0[n] = s0 * floorf(u[n] / s0);
  }
  apply_update(u, v0, sc1, v1);
  float q[8];
#pragma unroll
  for (int n = 0; n < 8; ++n) q[n] = u[n] - v1[n];
  SORTNET8V
  float dl[7]; float mx = 0.f;
#pragma unroll
  for (int g = 0; g < 7; ++g) { dl[g] = q[g + 1] - q[g]; mx = fmaxf(mx, dl[g]); }
  stats_block_reduce(dl, mx, &part[blockIdx.x]);
}

// ---------------- final: recompute v0 -> v1 -> v2, bf16, LDS transpose -> wT[n][l][k] --
__global__ void k_final_pack(const float* __restrict__ U,
                             const Scalars* __restrict__ sc0, const Scalars* __restrict__ sc1,
                             const Scalars* __restrict__ sc2, unsigned short* __restrict__ wT) {
  __shared__ unsigned short stile[8][32][34];
  int t = threadIdx.x;
  int k0 = (blockIdx.x >> 5) * 32;
  int l0 = (blockIdx.x & 31) * 32;
  float s0 = sc0->s;
  int kk = t >> 3;            // 0..31
  int lq = t & 7;             // 4 cols each
  int d0 = (k0 + kk) * 1024 + l0 + lq * 4;
  float4 u4[8];
#pragma unroll
  for (int n = 0; n < 8; ++n) u4[n] = *(const float4*)(U + ((size_t)n << 20) + d0);
#pragma unroll
  for (int j = 0; j < 4; ++j) {
    float u[8], v0[8], v1[8], v2[8];
#pragma unroll
    for (int n = 0; n < 8; ++n) {
      u[n] = ((const float*)&u4[n])[j];
      v0[n] = s0 * floorf(u[n] / s0);
    }
    apply_update(u, v0, sc1, v1);
    apply_update(u, v1, sc2, v2);
#pragma unroll
    for (int n = 0; n < 8; ++n) stile[n][kk][lq * 4 + j] = f2bf(v2[n]);
  }
  __syncthreads();
  // write wT[n][l][k]: thread -> ll = t>>3, kq = t&7 (4 k's, ushort4)
  int ll = t >> 3, kq = t & 7;
#pragma unroll
  for (int n = 0; n < 8; ++n) {
    ushort4 o;
    o.x = stile[n][kq * 4 + 0][ll];
    o.y = stile[n][kq * 4 + 1][ll];
    o.z = stile[n][kq * 4 + 2][ll];
    o.w = stile[n][kq * 4 + 3][ll];
    *(ushort4*)(wT + ((size_t)n << 20) + (size_t)(l0 + ll) * 1024 + k0 + kq * 4) = o;
  }
}

// ---------------- batched GEMM: out[b][n][l] = sum_k xT[n][b][k] * wT[n][l][k] ----------------
// n = blockIdx.x so XCD (= linear bid % 8) pins one ensemble member per XCD:
// xT_n (2MB) + wT_n (2MB) fit the 4MB per-XCD L2.
// 128x128 C-tile per block, BK=64, 4 waves (2x2 of 64x64), 16x16x32 bf16 MFMA.
// LDS stored as 16B chunks with XOR swizzle: chunk (row, cc) holds global (row, cc ^ (row&7)).
__global__ __launch_bounds__(256, 2)
void k_gemm(const unsigned short* __restrict__ xT, const unsigned short* __restrict__ wT,
            float* __restrict__ out) {
  __shared__ bf16x8 sA[1024];   // 128 rows x 8 chunks = 16 KB
  __shared__ bf16x8 sB[1024];
  const int n  = blockIdx.x;
  const int m0 = blockIdx.y * 128;
  const int l0 = blockIdx.z * 128;
  const int tid = threadIdx.x;
  const int lane = tid & 63;
  const int wv = tid >> 6;
  const int wm = (wv & 1) * 64;
  const int wl = (wv >> 1) * 64;
  const unsigned short* A  = xT + ((size_t)n << 20);
  const unsigned short* Bt = wT + ((size_t)n << 20);

  v4f acc[4][4] = {};
  const int quad = lane >> 4;
  const int r16 = lane & 15;

  for (int kt = 0; kt < 1024; kt += 64) {
#pragma unroll
    for (int rr = 0; rr < 4; ++rr) {
      int cb = rr * 4 + wv;            // chunk-block 0..15
      int c = cb * 64 + lane;          // chunk 0..1023
      int row = c >> 3;
      int gc = (c & 7) ^ (row & 7);    // swizzled source column
      const unsigned short* ga = A  + (size_t)(m0 + row) * 1024 + kt + gc * 8;
      const unsigned short* gb = Bt + (size_t)(l0 + row) * 1024 + kt + gc * 8;
      __builtin_amdgcn_global_load_lds((const __attribute__((address_space(1))) void*)ga,
                                       (__attribute__((address_space(3))) void*)&sA[cb * 64],
                                       16, 0, 0);
      __builtin_amdgcn_global_load_lds((const __attribute__((address_space(1))) void*)gb,
                                       (__attribute__((address_space(3))) void*)&sB[cb * 64],
                                       16, 0, 0);
    }
    asm volatile("s_waitcnt vmcnt(0)" ::: "memory");
    __syncthreads();

#pragma unroll
    for (int ks = 0; ks < 2; ++ks) {
      bf16x8 af[4], bfr[4];
#pragma unroll
      for (int t = 0; t < 4; ++t) {
        int arow = wm + t * 16 + r16;
        af[t] = sA[arow * 8 + ((ks * 4 + quad) ^ (arow & 7))];
        int brow = wl + t * 16 + r16;
        bfr[t] = sB[brow * 8 + ((ks * 4 + quad) ^ (brow & 7))];
      }
#pragma unroll
      for (int tm = 0; tm < 4; ++tm)
#pragma unroll
        for (int tn = 0; tn < 4; ++tn)
          acc[tm][tn] = __builtin_amdgcn_mfma_f32_16x16x32_bf16(af[tm], bfr[tn], acc[tm][tn], 0, 0, 0);
    }
    __syncthreads();
  }

  // epilogue: D[m=quad*4+reg][l=lane&15] per 16x16 tile
#pragma unroll
  for (int tm = 0; tm < 4; ++tm)
#pragma unroll
    for (int tn = 0; tn < 4; ++tn)
#pragma unroll
      for (int rr = 0; rr < 4; ++rr) {
        int row = m0 + wm + tm * 16 + quad * 4 + rr;
        int col = l0 + wl + tn * 16 + r16;
        out[(size_t)(row * 8 + n) * 1024 + col] = acc[tm][tn][rr];
      }
}

extern "C" void kernel_launch(void* const* d_in, const int* in_sizes, int n_in,
                              void* d_out, int out_size, void* d_ws, size_t ws_size,
                              hipStream_t stream) {
  const float* x = (const float*)d_in[0];
  const float* U = (const float*)d_in[1];
  const float* thres = (const float*)d_in[2];
  float* out = (float*)d_out;

  char* w = (char*)d_ws;
  Scalars* sc = (Scalars*)w;                                  // sc[0..2]
  float2* mmpart = (float2*)(w + 4096);                       // 8 KB
  unsigned short* xT = (unsigned short*)(w + 16384);          // 16 MB
  unsigned short* wT = xT + ((size_t)8 << 20);                // 16 MB
  Partial* part = (Partial*)(w + 16384 + ((size_t)32 << 20)); // 256 KB

  k_minmax_partial<<<1024, 256, 0, stream>>>((const float4*)U, mmpart);
  k_minmax_final<<<1, 256, 0, stream>>>(mmpart, &sc[0]);
  k_stats0<<<NPART + 2048, 256, 0, stream>>>(U, part, &sc[0], x, xT);
  k_scalars2<<<1, 256, 0, stream>>>(part, &sc[0], &sc[1], &sc[2], thres, 5.0f, 17.0f, 0);
  k_stats1<<<NPART, 256, 0, stream>>>(U, part, &sc[0], &sc[1], &sc[2]);
  k_scalars2<<<1, 256, 0, stream>>>(part, &sc[1], &sc[2], nullptr, thres, 17.0f, 0.0f, 1);
  k_final_pack<<<1024, 256, 0, stream>>>(U, &sc[0], &sc[1], &sc[2], wT);
  k_gemm<<<dim3(8, 8, 8), 256, 0, stream>>>(xT, wT, out);
}